// Round 17
// baseline (75.463 us; speedup 1.0000x reference)
//
#include <hip/hip_runtime.h>
#include <hip/hip_bf16.h>
#include <math.h>

namespace {

constexpr int Bb = 2, Ll = 2048, Dd = 512, Hh = 8;
constexpr int M = Bb * Ll;       // 4096
constexpr int THREE_D = 3 * Dd;  // 1536

typedef __attribute__((ext_vector_type(8))) short short8;
typedef __attribute__((ext_vector_type(4))) short short4v;
typedef __attribute__((ext_vector_type(4))) float f32x4;

__device__ __forceinline__ unsigned short f2bf(float x) {
  union { __hip_bfloat16 h; unsigned short u; } cv;
  cv.h = __float2bfloat16(x);
  return cv.u;
}

// raw v_exp_f32: computes 2^x in one VALU op (no ocml edge-case code)
__device__ __forceinline__ float fexp2(float x) {
  float r;
  asm("v_exp_f32 %0, %1" : "=v"(r) : "v"(x));
  return r;
}

__device__ __forceinline__ void gload_lds16(const void* g, void* l) {
  __builtin_amdgcn_global_load_lds(
      (const __attribute__((address_space(1))) void*)g,
      (__attribute__((address_space(3))) void*)l, 16, 0, 0);
}

// ---------------------------------------------------------------------------
// fp32 -> bf16 conversion for x, in_proj_w, out_proj_w (one fused kernel)
// ---------------------------------------------------------------------------
constexpr int QUADS_X = (M * Dd) / 4;        // 524288
constexpr int QUADS_W1 = (THREE_D * Dd) / 4; // 196608
constexpr int QUADS_W2 = (Dd * Dd) / 4;      // 65536
constexpr int QUADS_TOT = QUADS_X + QUADS_W1 + QUADS_W2;

__global__ __launch_bounds__(256) void cvt_bf16(
    const float* __restrict__ x, const float* __restrict__ w1,
    const float* __restrict__ w2, unsigned short* __restrict__ xb,
    unsigned short* __restrict__ wb, unsigned short* __restrict__ wob) {
  const int i = blockIdx.x * 256 + threadIdx.x;
  const float* src;
  unsigned short* dst;
  if (i < QUADS_X) {
    src = x + 4 * (size_t)i;
    dst = xb + 4 * (size_t)i;
  } else if (i < QUADS_X + QUADS_W1) {
    const int j = i - QUADS_X;
    src = w1 + 4 * (size_t)j;
    dst = wb + 4 * (size_t)j;
  } else {
    const int j = i - (QUADS_X + QUADS_W1);
    src = w2 + 4 * (size_t)j;
    dst = wob + 4 * (size_t)j;
  }
  float4 v = *reinterpret_cast<const float4*>(src);
  ushort4 o;
  o.x = f2bf(v.x); o.y = f2bf(v.y); o.z = f2bf(v.z); o.w = f2bf(v.w);
  *reinterpret_cast<ushort4*>(dst) = o;
}

// ---------------------------------------------------------------------------
// MFMA GEMM: C[M,N] = A[M,K] @ B[N,K]^T (+bias)(+residual), bf16 in, fp32 acc.
// BM x 128 tile (BM = 64 or 128), BK=64, 4 waves x (BM/2 x 64),
// global_load_lds w=16 with pre-swizzled source; ds_read_b128 with
// ((row&7)<<4) XOR swizzle. QKV q-section scale = 0.125 * log2(e) so the
// attention softmax can use base-2 exp directly (exact: max/sub commute).
// ---------------------------------------------------------------------------
template <int BM, int K, int N, bool QKV>
__global__ __launch_bounds__(256) void gemm_mfma(
    const unsigned short* __restrict__ A, const unsigned short* __restrict__ B,
    const float* __restrict__ bias, const float* __restrict__ R,
    unsigned short* __restrict__ Cb, float* __restrict__ Cf) {
  __shared__ unsigned short As[BM * 64];
  __shared__ unsigned short Bs[128 * 64];
  constexpr int MF = BM / 32;   // m-frags per wave (128->4, 64->2)
  constexpr int AL = BM / 32;   // A staging loads per wave

  const int tid = threadIdx.x;
  const int lane = tid & 63;
  const int wu = __builtin_amdgcn_readfirstlane(tid >> 6);
  const int q = lane & 15;
  const int g = lane >> 4;
  const int wr = wu >> 1, wc = wu & 1;
  const int m0 = blockIdx.y * BM, n0 = blockIdx.x * 128;

  const int srow = lane >> 3;
  const int scol = 8 * ((lane & 7) ^ srow);
  const unsigned short* Ag = A + (size_t)(m0 + (BM / 4) * wu + srow) * K + scol;
  const unsigned short* Bg = B + (size_t)(n0 + 32 * wu + srow) * K + scol;
  char* AsW = (char*)As + wu * (BM / 4) * 128;
  char* BsW = (char*)Bs + wu * 4096;

  f32x4 acc[MF][4] = {};

  for (int k0 = 0; k0 < K; k0 += 64) {
    __syncthreads();
#pragma unroll
    for (int i = 0; i < AL; ++i)
      gload_lds16(Ag + (size_t)(8 * i) * K + k0, AsW + 1024 * i);
#pragma unroll
    for (int i = 0; i < 4; ++i)
      gload_lds16(Bg + (size_t)(8 * i) * K + k0, BsW + 1024 * i);
    __syncthreads();

    const char* Abase = (const char*)As + (wr * (BM / 2) + q) * 128;
    const char* Bbase = (const char*)Bs + (wc * 64 + q) * 128;
#pragma unroll
    for (int s = 0; s < 2; ++s) {
      const int csw = (64 * s + 16 * g) ^ ((q & 7) << 4);
      short8 af[MF], bf[4];
#pragma unroll
      for (int m = 0; m < MF; ++m)
        af[m] = *reinterpret_cast<const short8*>(Abase + m * 2048 + csw);
#pragma unroll
      for (int n = 0; n < 4; ++n)
        bf[n] = *reinterpret_cast<const short8*>(Bbase + n * 2048 + csw);
#pragma unroll
      for (int m = 0; m < MF; ++m)
#pragma unroll
        for (int n = 0; n < 4; ++n)
          acc[m][n] = __builtin_amdgcn_mfma_f32_16x16x32_bf16(
              af[m], bf[n], acc[m][n], 0, 0, 0);
    }
  }

  const float sc = (QKV && n0 < Dd) ? 0.125f * 1.44269504f : 1.0f;
#pragma unroll
  for (int m = 0; m < MF; ++m) {
#pragma unroll
    for (int r = 0; r < 4; ++r) {
      const int row = m0 + wr * (BM / 2) + m * 16 + 4 * g + r;
#pragma unroll
      for (int n = 0; n < 4; ++n) {
        const int col = n0 + wc * 64 + n * 16 + q;
        const float v = acc[m][n][r] + bias[col];
        if (QKV) {
          Cb[(size_t)row * N + col] = f2bf(v * sc);
        } else {
          Cf[(size_t)row * N + col] = v + R[(size_t)row * N + col];
        }
      }
    }
  }
}

// ---------------------------------------------------------------------------
// MFMA flash attention v17 = round-15 verified math + TRUE 1-chunk-deep
// pipeline (T3/T4): K and V double-buffered; per iter: s_barrier (closes
// prev reads) -> issue ALL 4 gloads for t+1 -> vmcnt(4) (own t loads landed;
// t+1 stays in flight across the whole compute) -> s_barrier -> compute.
// NO vmcnt(0) in the loop. r5's failed variant had V staged at the bottom,
// whose mid-chunk counted wait FIFO-drained the K prefetch (never pipelined).
// Block = (b,h,64 q), 8 waves: wg=w&3 (16 q-rows), hv=w>>2 (kv half).
// LDS: K 32KB (dbuf) + V 32KB (dbuf) + P 16KB = 80KB (2 blocks/CU).
// ---------------------------------------------------------------------------
__global__ __launch_bounds__(512) void attn_mfma(
    const unsigned short* __restrict__ qkv, const int* __restrict__ wsz,
    unsigned short* __restrict__ ctx) {
  __shared__ unsigned short Kls[16384];  // 2 bufs x 2 halves x 8KB
  __shared__ unsigned short Vls[16384];
  __shared__ unsigned short Pls[8192];   // 8 waves x 2KB

  const int tid = threadIdx.x;
  const int lane = tid & 63;
  const int w = tid >> 6;
  const int wu = __builtin_amdgcn_readfirstlane(w);
  const int wg = wu & 3;   // q sub-tile within group
  const int hv = wu >> 2;  // kv half
  const int q = lane & 15;
  const int g = lane >> 4;

  const int qt = blockIdx.x & 31;
  const int h = (blockIdx.x >> 5) & 7;
  const int b = blockIdx.x >> 8;
  const int qbase = qt * 64;
  const int hwin = wsz[0] >> 1;

  const size_t bh_base = (size_t)b * Ll * THREE_D + h * 64;

  const unsigned short* qrow =
      qkv + bh_base + (size_t)(qbase + wg * 16 + q) * THREE_D;
  short8 qf0 = *reinterpret_cast<const short8*>(qrow + 8 * g);
  short8 qf1 = *reinterpret_cast<const short8*>(qrow + 32 + 8 * g);
  asm volatile("s_waitcnt vmcnt(0)" : "+v"(qf0), "+v"(qf1)::"memory");

  const int k_rowoff = wg * 16 + (lane >> 3);
  const int k_dcol = 8 * ((lane & 7) ^ ((lane >> 3) & 7));
  const unsigned short* kg_base = qkv + bh_base + Dd + k_dcol;

  const int v_rowoff = 32 * (wg >> 1) + 8 * ((lane >> 4) & 3) +
                       4 * ((lane >> 3) & 1) + ((lane >> 1) & 3);
  const unsigned short* vg_base = qkv + bh_base + 2 * Dd + 8 * (lane & 1);

  unsigned short* pw = &Pls[wu * 1024];
  char* pb = (char*)pw;

  f32x4 oacc[4] = {};
  float m_run = -1e30f, lp = 0.f;  // lp: lane-local partial row sum

  const int qlo = qbase + wg * 16;
  const int iq = qlo + q;  // this lane's q-row

  // staging helper offsets (buf-dependent base computed per call site)
#define STAGE(tile, buf)                                                     \
  {                                                                          \
    const int kb_ = hv * 1024 + (tile) * 64;                                 \
    unsigned short* kd_ = &Kls[(buf) * 8192 + hv * 4096 + wg * 1024];        \
    unsigned short* vd_ = &Vls[(buf) * 8192 + hv * 4096 + wg * 1024];        \
    gload_lds16(kg_base + (size_t)(kb_ + k_rowoff) * THREE_D, kd_);          \
    gload_lds16(kg_base + (size_t)(kb_ + k_rowoff + 8) * THREE_D,            \
                kd_ + 512);                                                  \
    gload_lds16(vg_base + (size_t)(kb_ + v_rowoff) * THREE_D +               \
                    16 * ((2 * wg + 0) & 3), vd_);                           \
    gload_lds16(vg_base + (size_t)(kb_ + v_rowoff) * THREE_D +               \
                    16 * ((2 * wg + 1) & 3), vd_ + 512);                     \
  }

  // ---- prologue: stage tile 0 into buf0 (stays in flight until t=0's wait)
  STAGE(0, 0);

  for (int t = 0; t < 16; ++t) {
    const int cur = t & 1;
    const int kbase = (hv * 16 + t) * 64;

    // barrier A: all waves done reading buf[1-cur] (iter t-1 compute; DS
    // drained by its final lgkmcnt(0)); safe to overwrite via staging.
    __builtin_amdgcn_s_barrier();

    if (t < 15) {
      STAGE(t + 1, cur ^ 1);
      // own tile-t loads (issued last iter) landed; t+1's 4 stay in flight
      asm volatile("s_waitcnt vmcnt(4)" ::: "memory");
    } else {
      asm volatile("s_waitcnt vmcnt(0)" ::: "memory");
    }
    __builtin_amdgcn_s_barrier();  // barrier B: tile t resident for all waves
    asm volatile("" ::: "memory"); // compiler fence: no hoisting above B

    const char* kbytes = (const char*)Kls + cur * 16384 + hv * 8192;
    const char* vbytes = (const char*)Vls + cur * 16384 + hv * 8192;

    // ---- S^T = K Q^T : lane (q,g) gets S[iq][kbase+16n+4g+r] (x log2e)
    f32x4 sa[4] = {};
    __builtin_amdgcn_s_setprio(1);
#pragma unroll
    for (int s = 0; s < 2; ++s) {
      const short8 qf = s ? qf1 : qf0;
#pragma unroll
      for (int n = 0; n < 4; ++n) {
        const int baddr =
            (((16 * n + q) * 128 + 64 * s + 16 * g)) ^ ((q & 7) << 4);
        const short8 kf = *reinterpret_cast<const short8*>(kbytes + baddr);
        sa[n] = __builtin_amdgcn_mfma_f32_16x16x32_bf16(kf, qf, sa[n], 0, 0, 0);
      }
    }
    __builtin_amdgcn_s_setprio(0);

    // ---- anti-local mask (j inside [i-hwin, i+hwin) -> -inf)
    if (kbase + 64 > qlo - hwin && kbase < qlo + 15 + hwin) {
#pragma unroll
      for (int n = 0; n < 4; ++n) {
#pragma unroll
        for (int r = 0; r < 4; ++r) {
          const int j = kbase + 16 * n + 4 * g + r;
          if (j >= iq - hwin && j < iq + hwin) sa[n][r] = -1e30f;
        }
      }
    }

    // ---- row max (max3-friendly trees), cross-g reduce
    float mx0 = fmaxf(fmaxf(fmaxf(sa[0][0], sa[0][1]), sa[0][2]), sa[0][3]);
    float mx1 = fmaxf(fmaxf(fmaxf(sa[1][0], sa[1][1]), sa[1][2]), sa[1][3]);
    float mx2 = fmaxf(fmaxf(fmaxf(sa[2][0], sa[2][1]), sa[2][2]), sa[2][3]);
    float mx3 = fmaxf(fmaxf(fmaxf(sa[3][0], sa[3][1]), sa[3][2]), sa[3][3]);
    float mx = fmaxf(fmaxf(fmaxf(mx0, mx1), mx2), mx3);
    mx = fmaxf(mx, __shfl_xor(mx, 16));
    mx = fmaxf(mx, __shfl_xor(mx, 32));

    // ---- defer-max (T13): rescale only when some row max grew by > 8
    if (!__all(mx <= m_run + 8.0f)) {
      const float mnew = fmaxf(m_run, mx);
      const float corr = fexp2(m_run - mnew);
      m_run = mnew;
      lp *= corr;
      float corr_o[4];
#pragma unroll
      for (int r = 0; r < 4; ++r) corr_o[r] = __shfl(corr, 4 * g + r, 16);
#pragma unroll
      for (int n = 0; n < 4; ++n)
#pragma unroll
        for (int r = 0; r < 4; ++r) oacc[n][r] *= corr_o[r];
    }

    // ---- P = 2^(S - m_run), lane-local partial sum
#pragma unroll
    for (int n = 0; n < 4; ++n)
#pragma unroll
      for (int r = 0; r < 4; ++r) sa[n][r] = fexp2(sa[n][r] - m_run);
    const float s0 = (sa[0][0] + sa[0][1]) + (sa[0][2] + sa[0][3]);
    const float s1 = (sa[1][0] + sa[1][1]) + (sa[1][2] + sa[1][3]);
    const float s2 = (sa[2][0] + sa[2][1]) + (sa[2][2] + sa[2][3]);
    const float s3 = (sa[3][0] + sa[3][1]) + (sa[3][2] + sa[3][3]);
    lp += (s0 + s1) + (s2 + s3);

    // ---- P -> LDS row-major [16 q][64 kv], XOR-swizzled, b64 per n
#pragma unroll
    for (int n = 0; n < 4; ++n) {
      uint2 pk;
      pk.x = (unsigned)f2bf(sa[n][0]) | ((unsigned)f2bf(sa[n][1]) << 16);
      pk.y = (unsigned)f2bf(sa[n][2]) | ((unsigned)f2bf(sa[n][3]) << 16);
      *reinterpret_cast<uint2*>(
          pb + q * 128 + ((32 * n + 8 * g) ^ ((q & 7) << 4))) = pk;
    }
    asm volatile("s_waitcnt lgkmcnt(0)" ::: "memory");  // P visible (same wave)

    // ---- O += P V : A = P (ds_read_b128), B = V (tr-reads)
#pragma unroll
    for (int s = 0; s < 2; ++s) {
      const short8 pf = *reinterpret_cast<const short8*>(
          pb + q * 128 + ((64 * s + 16 * g) ^ ((q & 7) << 4)));
      short4v vlo[4], vhi[4];
#pragma unroll
      for (int n = 0; n < 4; ++n) {
        const __attribute__((address_space(3))) unsigned short* va =
            (const __attribute__((address_space(3))) unsigned short*)(
                vbytes + 4096 * s + 1024 * n + 256 * g + 8 * q);
        asm volatile("ds_read_b64_tr_b16 %0, %1 offset:0" : "=v"(vlo[n]) : "v"(va));
        asm volatile("ds_read_b64_tr_b16 %0, %1 offset:128" : "=v"(vhi[n]) : "v"(va));
      }
      asm volatile("s_waitcnt lgkmcnt(0)"
                   : "+v"(vlo[0]), "+v"(vhi[0]), "+v"(vlo[1]), "+v"(vhi[1]),
                     "+v"(vlo[2]), "+v"(vhi[2]), "+v"(vlo[3]), "+v"(vhi[3])
                   :
                   : "memory");
      __builtin_amdgcn_sched_barrier(0);
      __builtin_amdgcn_s_setprio(1);
#pragma unroll
      for (int n = 0; n < 4; ++n) {
        const short8 vf =
            __builtin_shufflevector(vlo[n], vhi[n], 0, 1, 2, 3, 4, 5, 6, 7);
        oacc[n] = __builtin_amdgcn_mfma_f32_16x16x32_bf16(pf, vf, oacc[n], 0, 0, 0);
      }
      __builtin_amdgcn_s_setprio(0);
    }
  }
#undef STAGE

  // ---- finalize l: one cross-g reduce (deferred from the loop)
  lp += __shfl_xor(lp, 16);
  lp += __shfl_xor(lp, 32);
  const float l_run = lp;

  // ---- merge the two kv-half partials (exact flash combine), write ctx.
  float* Om = (float*)Kls;
  float* mls = (float*)Vls;

  __syncthreads();  // loop done; safe to reuse K/V LDS
  if (w >= 4) {
#pragma unroll
    for (int r = 0; r < 4; ++r) {
      const int rr = wg * 16 + 4 * g + r;
#pragma unroll
      for (int n = 0; n < 4; ++n) Om[rr * 64 + 16 * n + q] = oacc[n][r];
    }
    if (g == 0)
      *reinterpret_cast<float2*>(&mls[(wg * 16 + q) * 2]) =
          make_float2(m_run, l_run);
  }
  __syncthreads();
  if (w < 4) {
#pragma unroll
    for (int r = 0; r < 4; ++r) {
      const int rr = wg * 16 + 4 * g + r;
      const float m_own = __shfl(m_run, 4 * g + r, 16);
      const float l_own = __shfl(l_run, 4 * g + r, 16);
      const float2 ml2 = *reinterpret_cast<const float2*>(&mls[rr * 2]);
      const float ms = fmaxf(m_own, ml2.x);
      const float c1 = fexp2(m_own - ms);
      const float c2 = fexp2(ml2.x - ms);
      const float inv = 1.0f / (c1 * l_own + c2 * ml2.y);
      const int row = qbase + rr;
      unsigned short* crow = ctx + ((size_t)(b * Ll + row)) * Dd + h * 64 + q;
#pragma unroll
      for (int n = 0; n < 4; ++n) {
        const float o2 = Om[rr * 64 + 16 * n + q];
        crow[16 * n] = f2bf((c1 * oacc[n][r] + c2 * o2) * inv);
      }
    }
  }
}

// ---------------------------------------------------------------------------
// Row LayerNorm
// ---------------------------------------------------------------------------
__global__ __launch_bounds__(256) void ln_kernel(
    const float* __restrict__ y, const float* __restrict__ gamma,
    const float* __restrict__ beta, float* __restrict__ out) {
  const int row = blockIdx.x;
  const int tid = threadIdx.x;
  const float* yr = y + (size_t)row * Dd;

  float2 v = *reinterpret_cast<const float2*>(&yr[tid * 2]);
  float s = v.x + v.y;
  float qq = v.x * v.x + v.y * v.y;
#pragma unroll
  for (int off = 1; off < 64; off <<= 1) {
    s += __shfl_xor(s, off, 64);
    qq += __shfl_xor(qq, off, 64);
  }
  __shared__ float ss[4], qs[4];
  if ((tid & 63) == 0) { ss[tid >> 6] = s; qs[tid >> 6] = qq; }
  __syncthreads();
  s = (ss[0] + ss[1]) + (ss[2] + ss[3]);
  qq = (qs[0] + qs[1]) + (qs[2] + qs[3]);

  const float mu = s * (1.0f / Dd);
  const float var = qq * (1.0f / Dd) - mu * mu;
  const float rstd = rsqrtf(var + 1e-5f);

  float2 gmv = *reinterpret_cast<const float2*>(&gamma[tid * 2]);
  float2 bev = *reinterpret_cast<const float2*>(&beta[tid * 2]);
  float2 o;
  o.x = (v.x - mu) * rstd * gmv.x + bev.x;
  o.y = (v.y - mu) * rstd * gmv.y + bev.y;
  *reinterpret_cast<float2*>(&out[(size_t)row * Dd + tid * 2]) = o;
}

}  // namespace

extern "C" void kernel_launch(void* const* d_in, const int* in_sizes, int n_in,
                              void* d_out, int out_size, void* d_ws,
                              size_t ws_size, hipStream_t stream) {
  const float* x = (const float*)d_in[0];
  const float* w_in = (const float*)d_in[1];
  const float* b_in = (const float*)d_in[2];
  const float* w_out = (const float*)d_in[3];
  const float* b_out = (const float*)d_in[4];
  const float* gamma = (const float*)d_in[5];
  const float* beta = (const float*)d_in[6];
  const int* wsz = (const int*)d_in[7];
  float* out = (float*)d_out;

  unsigned short* ws16 = (unsigned short*)d_ws;
  unsigned short* qkvb = ws16;                       // 6291456 elems
  unsigned short* ctxb = ws16 + 6291456;             // 2097152
  unsigned short* xb = ws16 + 8388608;               // 2097152
  unsigned short* wb = ws16 + 10485760;              // 786432
  unsigned short* wob = ws16 + 11272192;             // 262144
  float* y = (float*)d_ws;  // aliases qkvb (dead after attention)

  dim3 blk(256);

  cvt_bf16<<<dim3(QUADS_TOT / 256), blk, 0, stream>>>(x, w_in, w_out, xb, wb,
                                                      wob);
  gemm_mfma<64, 512, 1536, true><<<dim3(12, 64), blk, 0, stream>>>(
      xb, wb, b_in, nullptr, qkvb, nullptr);
  attn_mfma<<<dim3(512), dim3(512), 0, stream>>>(qkvb, wsz, ctxb);
  gemm_mfma<64, 512, 512, false><<<dim3(4, 64), blk, 0, stream>>>(
      ctxb, wob, b_out, x, nullptr, y);
  ln_kernel<<<dim3(M), blk, 0, stream>>>(y, gamma, beta, out);
}

// Round 18
// 75.285 us; speedup vs baseline: 1.0024x; 1.0024x over previous
//
#include <hip/hip_runtime.h>
#include <hip/hip_bf16.h>
#include <math.h>

namespace {

constexpr int Bb = 2, Ll = 2048, Dd = 512, Hh = 8;
constexpr int M = Bb * Ll;       // 4096
constexpr int THREE_D = 3 * Dd;  // 1536

typedef __attribute__((ext_vector_type(8))) short short8;
typedef __attribute__((ext_vector_type(4))) short short4v;
typedef __attribute__((ext_vector_type(4))) float f32x4;

__device__ __forceinline__ unsigned short f2bf(float x) {
  union { __hip_bfloat16 h; unsigned short u; } cv;
  cv.h = __float2bfloat16(x);
  return cv.u;
}

// raw v_exp_f32: computes 2^x in one VALU op (no ocml edge-case code)
__device__ __forceinline__ float fexp2(float x) {
  float r;
  asm("v_exp_f32 %0, %1" : "=v"(r) : "v"(x));
  return r;
}

__device__ __forceinline__ void gload_lds16(const void* g, void* l) {
  __builtin_amdgcn_global_load_lds(
      (const __attribute__((address_space(1))) void*)g,
      (__attribute__((address_space(3))) void*)l, 16, 0, 0);
}

// ---------------------------------------------------------------------------
// fp32 -> bf16 conversion for the two weight matrices only (x is converted
// inline inside gemm_qkv's A-staging now).
// ---------------------------------------------------------------------------
constexpr int QUADS_W1 = (THREE_D * Dd) / 4; // 196608
constexpr int QUADS_W2 = (Dd * Dd) / 4;      // 65536
constexpr int QUADS_TOT = QUADS_W1 + QUADS_W2;  // 262144

__global__ __launch_bounds__(256) void cvt_bf16(
    const float* __restrict__ w1, const float* __restrict__ w2,
    unsigned short* __restrict__ wb, unsigned short* __restrict__ wob) {
  const int i = blockIdx.x * 256 + threadIdx.x;
  const float* src;
  unsigned short* dst;
  if (i < QUADS_W1) {
    src = w1 + 4 * (size_t)i;
    dst = wb + 4 * (size_t)i;
  } else {
    const int j = i - QUADS_W1;
    src = w2 + 4 * (size_t)j;
    dst = wob + 4 * (size_t)j;
  }
  float4 v = *reinterpret_cast<const float4*>(src);
  ushort4 o;
  o.x = f2bf(v.x); o.y = f2bf(v.y); o.z = f2bf(v.z); o.w = f2bf(v.w);
  *reinterpret_cast<ushort4*>(dst) = o;
}

// ---------------------------------------------------------------------------
// MFMA GEMM: C[M,N] = A[M,K] @ B[N,K]^T (+bias)(+residual), fp32 acc.
// BM x 128 tile, BK=64, 4 waves x (BM/2 x 64).
// MODE 1 (qkv): A read from fp32 x, converted inline during reg-staging
//   (float4 x2 -> bf16 pack -> swizzled ds_write_b128); out = bf16 with
//   q-section scale 0.125*log2e (base-2 softmax downstream; exact).
// MODE 0 (out_proj): A bf16 via global_load_lds; out = fp32 + bias + R.
// B always bf16 via global_load_lds w=16 with pre-swizzled source.
// ds_read_b128 with ((row&7)<<4) XOR swizzle on both operands.
// ---------------------------------------------------------------------------
template <int BM, int K, int N, int MODE>
__global__ __launch_bounds__(256) void gemm_mfma(
    const unsigned short* __restrict__ A, const float* __restrict__ Af,
    const unsigned short* __restrict__ B, const float* __restrict__ bias,
    const float* __restrict__ R, unsigned short* __restrict__ Cb,
    float* __restrict__ Cf) {
  __shared__ unsigned short As[BM * 64];
  __shared__ unsigned short Bs[128 * 64];
  constexpr int MF = BM / 32;   // m-frags per wave (64->2, 32->1)
  constexpr int AL = BM / 32;   // A staging loads per wave (MODE 0)

  const int tid = threadIdx.x;
  const int lane = tid & 63;
  const int wu = __builtin_amdgcn_readfirstlane(tid >> 6);
  const int q = lane & 15;
  const int g = lane >> 4;
  const int wr = wu >> 1, wc = wu & 1;
  const int m0 = blockIdx.y * BM, n0 = blockIdx.x * 128;

  const int srow = lane >> 3;
  const int scol = 8 * ((lane & 7) ^ srow);
  const unsigned short* Bg = B + (size_t)(n0 + 32 * wu + srow) * K + scol;
  char* BsW = (char*)Bs + wu * 4096;

  // MODE 0: A via global_load_lds (pre-swizzled source)
  const unsigned short* Ag =
      (MODE == 0) ? A + (size_t)(m0 + (BM / 4) * wu + srow) * K + scol
                  : nullptr;
  char* AsW = (char*)As + wu * (BM / 4) * 128;

  // MODE 1: A reg-staged from fp32 (row = 16*wu + (lane>>3) + 8h)
  const float* Agf =
      (MODE == 1)
          ? Af + (size_t)(m0 + 16 * wu + (lane >> 3)) * K + 8 * (lane & 7)
          : nullptr;
  char* AsWb = (char*)As + (16 * wu + (lane >> 3)) * 128 +
               16 * ((lane & 7) ^ (lane >> 3));

  f32x4 acc[MF][4] = {};

  for (int k0 = 0; k0 < K; k0 += 64) {
    __syncthreads();
#pragma unroll
    for (int i = 0; i < 4; ++i)
      gload_lds16(Bg + (size_t)(8 * i) * K + k0, BsW + 1024 * i);
    if (MODE == 0) {
#pragma unroll
      for (int i = 0; i < AL; ++i)
        gload_lds16(Ag + (size_t)(8 * i) * K + k0, AsW + 1024 * i);
    } else {
      // fp32 load + inline cvt + swizzled LDS write (2 half-tiles of 8 rows)
#pragma unroll
      for (int hh = 0; hh < 2; ++hh) {
        const float* ap = Agf + (size_t)(8 * hh) * K + k0;
        float4 a0 = *reinterpret_cast<const float4*>(ap);
        float4 a1 = *reinterpret_cast<const float4*>(ap + 4);
        short8 pk;
        pk[0] = (short)f2bf(a0.x); pk[1] = (short)f2bf(a0.y);
        pk[2] = (short)f2bf(a0.z); pk[3] = (short)f2bf(a0.w);
        pk[4] = (short)f2bf(a1.x); pk[5] = (short)f2bf(a1.y);
        pk[6] = (short)f2bf(a1.z); pk[7] = (short)f2bf(a1.w);
        *reinterpret_cast<short8*>(AsWb + 8 * hh * 128) = pk;
      }
    }
    __syncthreads();

    const char* Abase = (const char*)As + (wr * (BM / 2) + q) * 128;
    const char* Bbase = (const char*)Bs + (wc * 64 + q) * 128;
#pragma unroll
    for (int s = 0; s < 2; ++s) {
      const int csw = (64 * s + 16 * g) ^ ((q & 7) << 4);
      short8 af[MF], bf[4];
#pragma unroll
      for (int m = 0; m < MF; ++m)
        af[m] = *reinterpret_cast<const short8*>(Abase + m * 2048 + csw);
#pragma unroll
      for (int n = 0; n < 4; ++n)
        bf[n] = *reinterpret_cast<const short8*>(Bbase + n * 2048 + csw);
#pragma unroll
      for (int m = 0; m < MF; ++m)
#pragma unroll
        for (int n = 0; n < 4; ++n)
          acc[m][n] = __builtin_amdgcn_mfma_f32_16x16x32_bf16(
              af[m], bf[n], acc[m][n], 0, 0, 0);
    }
  }

  const float sc = (MODE == 1 && n0 < Dd) ? 0.125f * 1.44269504f : 1.0f;
#pragma unroll
  for (int m = 0; m < MF; ++m) {
#pragma unroll
    for (int r = 0; r < 4; ++r) {
      const int row = m0 + wr * (BM / 2) + m * 16 + 4 * g + r;
#pragma unroll
      for (int n = 0; n < 4; ++n) {
        const int col = n0 + wc * 64 + n * 16 + q;
        const float v = acc[m][n][r] + bias[col];
        if (MODE == 1) {
          Cb[(size_t)row * N + col] = f2bf(v * sc);
        } else {
          Cf[(size_t)row * N + col] = v + R[(size_t)row * N + col];
        }
      }
    }
  }
}

// ---------------------------------------------------------------------------
// MFMA flash attention, KVBLK=128 (round-16 verified best: 41.1us).
// Per 128-kv iteration: stage 2 sub-tiles, ONE QK^T phase (sa[8]), ONE mask
// check / max-reduce / defer-max branch / exp batch, PV in 2 sub-phases
// reusing the per-wave 2KB P buffer. Base-2 softmax via raw v_exp_f32 (Q
// carries 0.125*log2e); T13 defer-max THR=8; deferred l-reduction.
// Block = (b,h,64 q), 8 waves: wg=w&3, hv=w>>2 (kv half, 8 chunks).
// LDS: K 32KB + V 32KB + P 16KB = 80KB (2 blocks/CU, grid-pinned).
// ---------------------------------------------------------------------------
__global__ __launch_bounds__(512) void attn_mfma(
    const unsigned short* __restrict__ qkv, const int* __restrict__ wsz,
    unsigned short* __restrict__ ctx) {
  __shared__ unsigned short Kls[16384];  // 2 halves x 2 subtiles x [64][64]
  __shared__ unsigned short Vls[16384];  // 2 halves x 2 subtiles (tr layout)
  __shared__ unsigned short Pls[8192];   // 8 waves x 2KB

  const int tid = threadIdx.x;
  const int lane = tid & 63;
  const int w = tid >> 6;
  const int wu = __builtin_amdgcn_readfirstlane(w);
  const int wg = wu & 3;   // q sub-tile within group
  const int hv = wu >> 2;  // kv half
  const int q = lane & 15;
  const int g = lane >> 4;

  const int qt = blockIdx.x & 31;
  const int h = (blockIdx.x >> 5) & 7;
  const int b = blockIdx.x >> 8;
  const int qbase = qt * 64;
  const int hwin = wsz[0] >> 1;

  const size_t bh_base = (size_t)b * Ll * THREE_D + h * 64;

  const unsigned short* qrow =
      qkv + bh_base + (size_t)(qbase + wg * 16 + q) * THREE_D;
  short8 qf0 = *reinterpret_cast<const short8*>(qrow + 8 * g);
  short8 qf1 = *reinterpret_cast<const short8*>(qrow + 32 + 8 * g);
  asm volatile("s_waitcnt vmcnt(0)" : "+v"(qf0), "+v"(qf1)::"memory");

  const int k_rowoff = wg * 16 + (lane >> 3);
  const int k_dcol = 8 * ((lane & 7) ^ ((lane >> 3) & 7));
  const unsigned short* kg_base = qkv + bh_base + Dd + k_dcol;

  const int v_rowoff = 32 * (wg >> 1) + 8 * ((lane >> 4) & 3) +
                       4 * ((lane >> 3) & 1) + ((lane >> 1) & 3);
  const unsigned short* vg_base = qkv + bh_base + 2 * Dd + 8 * (lane & 1);

  // staging destinations: half hv at +8192 shorts, sub-tile u at +u*4096
  unsigned short* kst = &Kls[hv * 8192 + wg * 1024];
  unsigned short* vst = &Vls[hv * 8192 + wg * 1024];
  unsigned short* pw = &Pls[wu * 1024];
  const char* kbytes = (const char*)Kls + hv * 16384;
  const char* vbytes = (const char*)Vls + hv * 16384;
  char* pb = (char*)pw;

  f32x4 oacc[4] = {};
  float m_run = -1e30f, lp = 0.f;  // lp: lane-local partial row sum

  const int qlo = qbase + wg * 16;
  const int iq = qlo + q;  // this lane's q-row

  for (int t = 0; t < 8; ++t) {
    const int kbase = hv * 1024 + t * 128;
    __syncthreads();  // prior chunk's readers done

#pragma unroll
    for (int u = 0; u < 2; ++u) {
      const int kb = kbase + u * 64;
      gload_lds16(kg_base + (size_t)(kb + k_rowoff) * THREE_D, kst + u * 4096);
      gload_lds16(kg_base + (size_t)(kb + k_rowoff + 8) * THREE_D,
                  kst + u * 4096 + 512);
      gload_lds16(vg_base + (size_t)(kb + v_rowoff) * THREE_D +
                      16 * ((2 * wg + 0) & 3), vst + u * 4096);
      gload_lds16(vg_base + (size_t)(kb + v_rowoff) * THREE_D +
                      16 * ((2 * wg + 1) & 3), vst + u * 4096 + 512);
    }
    __syncthreads();  // both sub-tiles resident

    // ---- S^T = K Q^T over 128 kv: lane (q,g) gets S[iq][kbase+16n+4g+r]
    f32x4 sa[8] = {};
    __builtin_amdgcn_s_setprio(1);
#pragma unroll
    for (int s = 0; s < 2; ++s) {
      const short8 qf = s ? qf1 : qf0;
#pragma unroll
      for (int n = 0; n < 8; ++n) {
        const int u = n >> 2, nn = n & 3;
        const int baddr =
            u * 8192 + ((((16 * nn + q) * 128 + 64 * s + 16 * g)) ^
                        ((q & 7) << 4));
        const short8 kf = *reinterpret_cast<const short8*>(kbytes + baddr);
        sa[n] = __builtin_amdgcn_mfma_f32_16x16x32_bf16(kf, qf, sa[n], 0, 0, 0);
      }
    }
    __builtin_amdgcn_s_setprio(0);

    // ---- anti-local mask (j inside [i-hwin, i+hwin) -> -inf)
    if (kbase + 128 > qlo - hwin && kbase < qlo + 15 + hwin) {
#pragma unroll
      for (int n = 0; n < 8; ++n) {
#pragma unroll
        for (int r = 0; r < 4; ++r) {
          const int j = kbase + 16 * n + 4 * g + r;
          if (j >= iq - hwin && j < iq + hwin) sa[n][r] = -1e30f;
        }
      }
    }

    // ---- row max over 32 values (max3-friendly trees), cross-g reduce
    float mxa[8];
#pragma unroll
    for (int n = 0; n < 8; ++n)
      mxa[n] = fmaxf(fmaxf(fmaxf(sa[n][0], sa[n][1]), sa[n][2]), sa[n][3]);
    float mx = fmaxf(
        fmaxf(fmaxf(mxa[0], mxa[1]), fmaxf(mxa[2], mxa[3])),
        fmaxf(fmaxf(mxa[4], mxa[5]), fmaxf(mxa[6], mxa[7])));
    mx = fmaxf(mx, __shfl_xor(mx, 16));
    mx = fmaxf(mx, __shfl_xor(mx, 32));

    // ---- defer-max (T13): rescale only when some row max grew by > 8
    if (!__all(mx <= m_run + 8.0f)) {
      const float mnew = fmaxf(m_run, mx);
      const float corr = fexp2(m_run - mnew);
      m_run = mnew;
      lp *= corr;
      float corr_o[4];
#pragma unroll
      for (int r = 0; r < 4; ++r) corr_o[r] = __shfl(corr, 4 * g + r, 16);
#pragma unroll
      for (int n = 0; n < 4; ++n)
#pragma unroll
        for (int r = 0; r < 4; ++r) oacc[n][r] *= corr_o[r];
    }

    // ---- P = 2^(S - m_run), lane-local partial sum
#pragma unroll
    for (int n = 0; n < 8; ++n)
#pragma unroll
      for (int r = 0; r < 4; ++r) sa[n][r] = fexp2(sa[n][r] - m_run);
#pragma unroll
    for (int n = 0; n < 8; ++n)
      lp += (sa[n][0] + sa[n][1]) + (sa[n][2] + sa[n][3]);

    // ---- PV in 2 sub-phases (P buffer reused; DS ops in-order per wave)
#pragma unroll
    for (int u = 0; u < 2; ++u) {
#pragma unroll
      for (int n = 0; n < 4; ++n) {
        const f32x4 sv = sa[4 * u + n];
        uint2 pk;
        pk.x = (unsigned)f2bf(sv[0]) | ((unsigned)f2bf(sv[1]) << 16);
        pk.y = (unsigned)f2bf(sv[2]) | ((unsigned)f2bf(sv[3]) << 16);
        *reinterpret_cast<uint2*>(
            pb + q * 128 + ((32 * n + 8 * g) ^ ((q & 7) << 4))) = pk;
      }
      asm volatile("s_waitcnt lgkmcnt(0)" ::: "memory");  // P visible

#pragma unroll
      for (int s = 0; s < 2; ++s) {
        const short8 pf = *reinterpret_cast<const short8*>(
            pb + q * 128 + ((64 * s + 16 * g) ^ ((q & 7) << 4)));
        short4v vlo[4], vhi[4];
#pragma unroll
        for (int n = 0; n < 4; ++n) {
          const __attribute__((address_space(3))) unsigned short* va =
              (const __attribute__((address_space(3))) unsigned short*)(
                  vbytes + u * 8192 + 4096 * s + 1024 * n + 256 * g + 8 * q);
          asm volatile("ds_read_b64_tr_b16 %0, %1 offset:0" : "=v"(vlo[n]) : "v"(va));
          asm volatile("ds_read_b64_tr_b16 %0, %1 offset:128" : "=v"(vhi[n]) : "v"(va));
        }
        asm volatile("s_waitcnt lgkmcnt(0)"
                     : "+v"(vlo[0]), "+v"(vhi[0]), "+v"(vlo[1]), "+v"(vhi[1]),
                       "+v"(vlo[2]), "+v"(vhi[2]), "+v"(vlo[3]), "+v"(vhi[3])
                     :
                     : "memory");
        __builtin_amdgcn_sched_barrier(0);
        __builtin_amdgcn_s_setprio(1);
#pragma unroll
        for (int n = 0; n < 4; ++n) {
          const short8 vf = __builtin_shufflevector(vlo[n], vhi[n], 0, 1, 2, 3,
                                                    4, 5, 6, 7);
          oacc[n] =
              __builtin_amdgcn_mfma_f32_16x16x32_bf16(pf, vf, oacc[n], 0, 0, 0);
        }
        __builtin_amdgcn_s_setprio(0);
      }
    }
  }

  // ---- finalize l: one cross-g reduce (deferred from the loop)
  lp += __shfl_xor(lp, 16);
  lp += __shfl_xor(lp, 32);
  const float l_run = lp;

  // ---- merge the two kv-half partials (exact flash combine), write ctx.
  float* Om = (float*)Kls;
  float* mls = (float*)Vls;

  __syncthreads();  // loop done; safe to reuse K/V LDS
  if (w >= 4) {
#pragma unroll
    for (int r = 0; r < 4; ++r) {
      const int rr = wg * 16 + 4 * g + r;
#pragma unroll
      for (int n = 0; n < 4; ++n) Om[rr * 64 + 16 * n + q] = oacc[n][r];
    }
    if (g == 0)
      *reinterpret_cast<float2*>(&mls[(wg * 16 + q) * 2]) =
          make_float2(m_run, l_run);
  }
  __syncthreads();
  if (w < 4) {
#pragma unroll
    for (int r = 0; r < 4; ++r) {
      const int rr = wg * 16 + 4 * g + r;
      const float m_own = __shfl(m_run, 4 * g + r, 16);
      const float l_own = __shfl(l_run, 4 * g + r, 16);
      const float2 ml2 = *reinterpret_cast<const float2*>(&mls[rr * 2]);
      const float ms = fmaxf(m_own, ml2.x);
      const float c1 = fexp2(m_own - ms);
      const float c2 = fexp2(ml2.x - ms);
      const float inv = 1.0f / (c1 * l_own + c2 * ml2.y);
      const int row = qbase + rr;
      unsigned short* crow = ctx + ((size_t)(b * Ll + row)) * Dd + h * 64 + q;
#pragma unroll
      for (int n = 0; n < 4; ++n) {
        const float o2 = Om[rr * 64 + 16 * n + q];
        crow[16 * n] = f2bf((c1 * oacc[n][r] + c2 * o2) * inv);
      }
    }
  }
}

// ---------------------------------------------------------------------------
// Row LayerNorm
// ---------------------------------------------------------------------------
__global__ __launch_bounds__(256) void ln_kernel(
    const float* __restrict__ y, const float* __restrict__ gamma,
    const float* __restrict__ beta, float* __restrict__ out) {
  const int row = blockIdx.x;
  const int tid = threadIdx.x;
  const float* yr = y + (size_t)row * Dd;

  float2 v = *reinterpret_cast<const float2*>(&yr[tid * 2]);
  float s = v.x + v.y;
  float qq = v.x * v.x + v.y * v.y;
#pragma unroll
  for (int off = 1; off < 64; off <<= 1) {
    s += __shfl_xor(s, off, 64);
    qq += __shfl_xor(qq, off, 64);
  }
  __shared__ float ss[4], qs[4];
  if ((tid & 63) == 0) { ss[tid >> 6] = s; qs[tid >> 6] = qq; }
  __syncthreads();
  s = (ss[0] + ss[1]) + (ss[2] + ss[3]);
  qq = (qs[0] + qs[1]) + (qs[2] + qs[3]);

  const float mu = s * (1.0f / Dd);
  const float var = qq * (1.0f / Dd) - mu * mu;
  const float rstd = rsqrtf(var + 1e-5f);

  float2 gmv = *reinterpret_cast<const float2*>(&gamma[tid * 2]);
  float2 bev = *reinterpret_cast<const float2*>(&beta[tid * 2]);
  float2 o;
  o.x = (v.x - mu) * rstd * gmv.x + bev.x;
  o.y = (v.y - mu) * rstd * gmv.y + bev.y;
  *reinterpret_cast<float2*>(&out[(size_t)row * Dd + tid * 2]) = o;
}

}  // namespace

extern "C" void kernel_launch(void* const* d_in, const int* in_sizes, int n_in,
                              void* d_out, int out_size, void* d_ws,
                              size_t ws_size, hipStream_t stream) {
  const float* x = (const float*)d_in[0];
  const float* w_in = (const float*)d_in[1];
  const float* b_in = (const float*)d_in[2];
  const float* w_out = (const float*)d_in[3];
  const float* b_out = (const float*)d_in[4];
  const float* gamma = (const float*)d_in[5];
  const float* beta = (const float*)d_in[6];
  const int* wsz = (const int*)d_in[7];
  float* out = (float*)d_out;

  unsigned short* ws16 = (unsigned short*)d_ws;
  unsigned short* qkvb = ws16;                       // 6291456 elems
  unsigned short* ctxb = ws16 + 6291456;             // 2097152
  unsigned short* wb = ws16 + 10485760;              // 786432
  unsigned short* wob = ws16 + 11272192;             // 262144
  float* y = (float*)d_ws;  // aliases qkvb (dead after attention)

  dim3 blk(256);

  cvt_bf16<<<dim3(QUADS_TOT / 256), blk, 0, stream>>>(w_in, w_out, wb, wob);
  gemm_mfma<64, 512, 1536, 1><<<dim3(12, 64), blk, 0, stream>>>(
      nullptr, x, wb, b_in, nullptr, qkvb, nullptr);
  attn_mfma<<<dim3(512), dim3(512), 0, stream>>>(qkvb, wsz, ctxb);
  gemm_mfma<32, 512, 512, 0><<<dim3(4, 128), blk, 0, stream>>>(
      ctxb, nullptr, wob, b_out, x, nullptr, y);
  ln_kernel<<<dim3(M), blk, 0, stream>>>(y, gamma, beta, out);
}

// Round 19
// 72.597 us; speedup vs baseline: 1.0395x; 1.0370x over previous
//
#include <hip/hip_runtime.h>
#include <hip/hip_bf16.h>
#include <math.h>

namespace {

constexpr int Bb = 2, Ll = 2048, Dd = 512, Hh = 8;
constexpr int M = Bb * Ll;       // 4096
constexpr int THREE_D = 3 * Dd;  // 1536

typedef __attribute__((ext_vector_type(8))) short short8;
typedef __attribute__((ext_vector_type(4))) short short4v;
typedef __attribute__((ext_vector_type(4))) float f32x4;

__device__ __forceinline__ unsigned short f2bf(float x) {
  union { __hip_bfloat16 h; unsigned short u; } cv;
  cv.h = __float2bfloat16(x);
  return cv.u;
}

// raw v_exp_f32: computes 2^x in one VALU op (no ocml edge-case code)
__device__ __forceinline__ float fexp2(float x) {
  float r;
  asm("v_exp_f32 %0, %1" : "=v"(r) : "v"(x));
  return r;
}

__device__ __forceinline__ void gload_lds16(const void* g, void* l) {
  __builtin_amdgcn_global_load_lds(
      (const __attribute__((address_space(1))) void*)g,
      (__attribute__((address_space(3))) void*)l, 16, 0, 0);
}

// ---------------------------------------------------------------------------
// fp32 -> bf16 conversion for x, in_proj_w, out_proj_w (one fused kernel)
// ---------------------------------------------------------------------------
constexpr int QUADS_X = (M * Dd) / 4;        // 524288
constexpr int QUADS_W1 = (THREE_D * Dd) / 4; // 196608
constexpr int QUADS_W2 = (Dd * Dd) / 4;      // 65536
constexpr int QUADS_TOT = QUADS_X + QUADS_W1 + QUADS_W2;

__global__ __launch_bounds__(256) void cvt_bf16(
    const float* __restrict__ x, const float* __restrict__ w1,
    const float* __restrict__ w2, unsigned short* __restrict__ xb,
    unsigned short* __restrict__ wb, unsigned short* __restrict__ wob) {
  const int i = blockIdx.x * 256 + threadIdx.x;
  const float* src;
  unsigned short* dst;
  if (i < QUADS_X) {
    src = x + 4 * (size_t)i;
    dst = xb + 4 * (size_t)i;
  } else if (i < QUADS_X + QUADS_W1) {
    const int j = i - QUADS_X;
    src = w1 + 4 * (size_t)j;
    dst = wb + 4 * (size_t)j;
  } else {
    const int j = i - (QUADS_X + QUADS_W1);
    src = w2 + 4 * (size_t)j;
    dst = wob + 4 * (size_t)j;
  }
  float4 v = *reinterpret_cast<const float4*>(src);
  ushort4 o;
  o.x = f2bf(v.x); o.y = f2bf(v.y); o.z = f2bf(v.z); o.w = f2bf(v.w);
  *reinterpret_cast<ushort4*>(dst) = o;
}

// ---------------------------------------------------------------------------
// MFMA GEMM: C[M,N] = A[M,K] @ B[N,K]^T (+bias)(+residual), bf16 in, fp32 acc.
// BM x 128 tile (BM = 64 or 128), BK=64, 4 waves x (BM/2 x 64),
// global_load_lds w=16 with pre-swizzled source; ds_read_b128 with
// ((row&7)<<4) XOR swizzle. QKV q-section scale = 0.125 * log2(e) so the
// attention softmax can use base-2 exp directly (exact: max/sub commute).
// ---------------------------------------------------------------------------
template <int BM, int K, int N, bool QKV>
__global__ __launch_bounds__(256) void gemm_mfma(
    const unsigned short* __restrict__ A, const unsigned short* __restrict__ B,
    const float* __restrict__ bias, const float* __restrict__ R,
    unsigned short* __restrict__ Cb, float* __restrict__ Cf) {
  __shared__ unsigned short As[BM * 64];
  __shared__ unsigned short Bs[128 * 64];
  constexpr int MF = BM / 32;   // m-frags per wave (128->4, 64->2)
  constexpr int AL = BM / 32;   // A staging loads per wave

  const int tid = threadIdx.x;
  const int lane = tid & 63;
  const int wu = __builtin_amdgcn_readfirstlane(tid >> 6);
  const int q = lane & 15;
  const int g = lane >> 4;
  const int wr = wu >> 1, wc = wu & 1;
  const int m0 = blockIdx.y * BM, n0 = blockIdx.x * 128;

  const int srow = lane >> 3;
  const int scol = 8 * ((lane & 7) ^ srow);
  const unsigned short* Ag = A + (size_t)(m0 + (BM / 4) * wu + srow) * K + scol;
  const unsigned short* Bg = B + (size_t)(n0 + 32 * wu + srow) * K + scol;
  char* AsW = (char*)As + wu * (BM / 4) * 128;
  char* BsW = (char*)Bs + wu * 4096;

  f32x4 acc[MF][4] = {};

  for (int k0 = 0; k0 < K; k0 += 64) {
    __syncthreads();
#pragma unroll
    for (int i = 0; i < AL; ++i)
      gload_lds16(Ag + (size_t)(8 * i) * K + k0, AsW + 1024 * i);
#pragma unroll
    for (int i = 0; i < 4; ++i)
      gload_lds16(Bg + (size_t)(8 * i) * K + k0, BsW + 1024 * i);
    __syncthreads();

    const char* Abase = (const char*)As + (wr * (BM / 2) + q) * 128;
    const char* Bbase = (const char*)Bs + (wc * 64 + q) * 128;
#pragma unroll
    for (int s = 0; s < 2; ++s) {
      const int csw = (64 * s + 16 * g) ^ ((q & 7) << 4);
      short8 af[MF], bf[4];
#pragma unroll
      for (int m = 0; m < MF; ++m)
        af[m] = *reinterpret_cast<const short8*>(Abase + m * 2048 + csw);
#pragma unroll
      for (int n = 0; n < 4; ++n)
        bf[n] = *reinterpret_cast<const short8*>(Bbase + n * 2048 + csw);
#pragma unroll
      for (int m = 0; m < MF; ++m)
#pragma unroll
        for (int n = 0; n < 4; ++n)
          acc[m][n] = __builtin_amdgcn_mfma_f32_16x16x32_bf16(
              af[m], bf[n], acc[m][n], 0, 0, 0);
    }
  }

  const float sc = (QKV && n0 < Dd) ? 0.125f * 1.44269504f : 1.0f;
#pragma unroll
  for (int m = 0; m < MF; ++m) {
#pragma unroll
    for (int r = 0; r < 4; ++r) {
      const int row = m0 + wr * (BM / 2) + m * 16 + 4 * g + r;
#pragma unroll
      for (int n = 0; n < 4; ++n) {
        const int col = n0 + wc * 64 + n * 16 + q;
        const float v = acc[m][n][r] + bias[col];
        if (QKV) {
          Cb[(size_t)row * N + col] = f2bf(v * sc);
        } else {
          Cf[(size_t)row * N + col] = v + R[(size_t)row * N + col];
        }
      }
    }
  }
}

// ---------------------------------------------------------------------------
// MFMA flash attention, KVBLK=128 (round-16 verified best: 41.1us).
// Per 128-kv iteration: stage 2 sub-tiles, ONE QK^T phase (sa[8]), ONE mask
// check / max-reduce / defer-max branch / exp batch, PV in 2 sub-phases
// reusing the per-wave 2KB P buffer. Base-2 softmax via raw v_exp_f32 (Q
// carries 0.125*log2e); T13 defer-max THR=8; deferred l-reduction.
// Block = (b,h,64 q), 8 waves: wg=w&3, hv=w>>2 (kv half, 8 chunks).
// LDS: K 32KB + V 32KB + P 16KB = 80KB (2 blocks/CU, grid-pinned).
// ---------------------------------------------------------------------------
__global__ __launch_bounds__(512) void attn_mfma(
    const unsigned short* __restrict__ qkv, const int* __restrict__ wsz,
    unsigned short* __restrict__ ctx) {
  __shared__ unsigned short Kls[16384];  // 2 halves x 2 subtiles x [64][64]
  __shared__ unsigned short Vls[16384];  // 2 halves x 2 subtiles (tr layout)
  __shared__ unsigned short Pls[8192];   // 8 waves x 2KB

  const int tid = threadIdx.x;
  const int lane = tid & 63;
  const int w = tid >> 6;
  const int wu = __builtin_amdgcn_readfirstlane(w);
  const int wg = wu & 3;   // q sub-tile within group
  const int hv = wu >> 2;  // kv half
  const int q = lane & 15;
  const int g = lane >> 4;

  const int qt = blockIdx.x & 31;
  const int h = (blockIdx.x >> 5) & 7;
  const int b = blockIdx.x >> 8;
  const int qbase = qt * 64;
  const int hwin = wsz[0] >> 1;

  const size_t bh_base = (size_t)b * Ll * THREE_D + h * 64;

  const unsigned short* qrow =
      qkv + bh_base + (size_t)(qbase + wg * 16 + q) * THREE_D;
  short8 qf0 = *reinterpret_cast<const short8*>(qrow + 8 * g);
  short8 qf1 = *reinterpret_cast<const short8*>(qrow + 32 + 8 * g);
  asm volatile("s_waitcnt vmcnt(0)" : "+v"(qf0), "+v"(qf1)::"memory");

  const int k_rowoff = wg * 16 + (lane >> 3);
  const int k_dcol = 8 * ((lane & 7) ^ ((lane >> 3) & 7));
  const unsigned short* kg_base = qkv + bh_base + Dd + k_dcol;

  const int v_rowoff = 32 * (wg >> 1) + 8 * ((lane >> 4) & 3) +
                       4 * ((lane >> 3) & 1) + ((lane >> 1) & 3);
  const unsigned short* vg_base = qkv + bh_base + 2 * Dd + 8 * (lane & 1);

  // staging destinations: half hv at +8192 shorts, sub-tile u at +u*4096
  unsigned short* kst = &Kls[hv * 8192 + wg * 1024];
  unsigned short* vst = &Vls[hv * 8192 + wg * 1024];
  unsigned short* pw = &Pls[wu * 1024];
  const char* kbytes = (const char*)Kls + hv * 16384;
  const char* vbytes = (const char*)Vls + hv * 16384;
  char* pb = (char*)pw;

  f32x4 oacc[4] = {};
  float m_run = -1e30f, lp = 0.f;  // lp: lane-local partial row sum

  const int qlo = qbase + wg * 16;
  const int iq = qlo + q;  // this lane's q-row

  for (int t = 0; t < 8; ++t) {
    const int kbase = hv * 1024 + t * 128;
    __syncthreads();  // prior chunk's readers done

#pragma unroll
    for (int u = 0; u < 2; ++u) {
      const int kb = kbase + u * 64;
      gload_lds16(kg_base + (size_t)(kb + k_rowoff) * THREE_D, kst + u * 4096);
      gload_lds16(kg_base + (size_t)(kb + k_rowoff + 8) * THREE_D,
                  kst + u * 4096 + 512);
      gload_lds16(vg_base + (size_t)(kb + v_rowoff) * THREE_D +
                      16 * ((2 * wg + 0) & 3), vst + u * 4096);
      gload_lds16(vg_base + (size_t)(kb + v_rowoff) * THREE_D +
                      16 * ((2 * wg + 1) & 3), vst + u * 4096 + 512);
    }
    __syncthreads();  // both sub-tiles resident

    // ---- S^T = K Q^T over 128 kv: lane (q,g) gets S[iq][kbase+16n+4g+r]
    f32x4 sa[8] = {};
    __builtin_amdgcn_s_setprio(1);
#pragma unroll
    for (int s = 0; s < 2; ++s) {
      const short8 qf = s ? qf1 : qf0;
#pragma unroll
      for (int n = 0; n < 8; ++n) {
        const int u = n >> 2, nn = n & 3;
        const int baddr =
            u * 8192 + ((((16 * nn + q) * 128 + 64 * s + 16 * g)) ^
                        ((q & 7) << 4));
        const short8 kf = *reinterpret_cast<const short8*>(kbytes + baddr);
        sa[n] = __builtin_amdgcn_mfma_f32_16x16x32_bf16(kf, qf, sa[n], 0, 0, 0);
      }
    }
    __builtin_amdgcn_s_setprio(0);

    // ---- anti-local mask (j inside [i-hwin, i+hwin) -> -inf)
    if (kbase + 128 > qlo - hwin && kbase < qlo + 15 + hwin) {
#pragma unroll
      for (int n = 0; n < 8; ++n) {
#pragma unroll
        for (int r = 0; r < 4; ++r) {
          const int j = kbase + 16 * n + 4 * g + r;
          if (j >= iq - hwin && j < iq + hwin) sa[n][r] = -1e30f;
        }
      }
    }

    // ---- row max over 32 values (max3-friendly trees), cross-g reduce
    float mxa[8];
#pragma unroll
    for (int n = 0; n < 8; ++n)
      mxa[n] = fmaxf(fmaxf(fmaxf(sa[n][0], sa[n][1]), sa[n][2]), sa[n][3]);
    float mx = fmaxf(
        fmaxf(fmaxf(mxa[0], mxa[1]), fmaxf(mxa[2], mxa[3])),
        fmaxf(fmaxf(mxa[4], mxa[5]), fmaxf(mxa[6], mxa[7])));
    mx = fmaxf(mx, __shfl_xor(mx, 16));
    mx = fmaxf(mx, __shfl_xor(mx, 32));

    // ---- defer-max (T13): rescale only when some row max grew by > 8
    if (!__all(mx <= m_run + 8.0f)) {
      const float mnew = fmaxf(m_run, mx);
      const float corr = fexp2(m_run - mnew);
      m_run = mnew;
      lp *= corr;
      float corr_o[4];
#pragma unroll
      for (int r = 0; r < 4; ++r) corr_o[r] = __shfl(corr, 4 * g + r, 16);
#pragma unroll
      for (int n = 0; n < 4; ++n)
#pragma unroll
        for (int r = 0; r < 4; ++r) oacc[n][r] *= corr_o[r];
    }

    // ---- P = 2^(S - m_run), lane-local partial sum
#pragma unroll
    for (int n = 0; n < 8; ++n)
#pragma unroll
      for (int r = 0; r < 4; ++r) sa[n][r] = fexp2(sa[n][r] - m_run);
#pragma unroll
    for (int n = 0; n < 8; ++n)
      lp += (sa[n][0] + sa[n][1]) + (sa[n][2] + sa[n][3]);

    // ---- PV in 2 sub-phases (P buffer reused; DS ops in-order per wave)
#pragma unroll
    for (int u = 0; u < 2; ++u) {
#pragma unroll
      for (int n = 0; n < 4; ++n) {
        const f32x4 sv = sa[4 * u + n];
        uint2 pk;
        pk.x = (unsigned)f2bf(sv[0]) | ((unsigned)f2bf(sv[1]) << 16);
        pk.y = (unsigned)f2bf(sv[2]) | ((unsigned)f2bf(sv[3]) << 16);
        *reinterpret_cast<uint2*>(
            pb + q * 128 + ((32 * n + 8 * g) ^ ((q & 7) << 4))) = pk;
      }
      asm volatile("s_waitcnt lgkmcnt(0)" ::: "memory");  // P visible

#pragma unroll
      for (int s = 0; s < 2; ++s) {
        const short8 pf = *reinterpret_cast<const short8*>(
            pb + q * 128 + ((64 * s + 16 * g) ^ ((q & 7) << 4)));
        short4v vlo[4], vhi[4];
#pragma unroll
        for (int n = 0; n < 4; ++n) {
          const __attribute__((address_space(3))) unsigned short* va =
              (const __attribute__((address_space(3))) unsigned short*)(
                  vbytes + u * 8192 + 4096 * s + 1024 * n + 256 * g + 8 * q);
          asm volatile("ds_read_b64_tr_b16 %0, %1 offset:0" : "=v"(vlo[n]) : "v"(va));
          asm volatile("ds_read_b64_tr_b16 %0, %1 offset:128" : "=v"(vhi[n]) : "v"(va));
        }
        asm volatile("s_waitcnt lgkmcnt(0)"
                     : "+v"(vlo[0]), "+v"(vhi[0]), "+v"(vlo[1]), "+v"(vhi[1]),
                       "+v"(vlo[2]), "+v"(vhi[2]), "+v"(vlo[3]), "+v"(vhi[3])
                     :
                     : "memory");
        __builtin_amdgcn_sched_barrier(0);
        __builtin_amdgcn_s_setprio(1);
#pragma unroll
        for (int n = 0; n < 4; ++n) {
          const short8 vf = __builtin_shufflevector(vlo[n], vhi[n], 0, 1, 2, 3,
                                                    4, 5, 6, 7);
          oacc[n] =
              __builtin_amdgcn_mfma_f32_16x16x32_bf16(pf, vf, oacc[n], 0, 0, 0);
        }
        __builtin_amdgcn_s_setprio(0);
      }
    }
  }

  // ---- finalize l: one cross-g reduce (deferred from the loop)
  lp += __shfl_xor(lp, 16);
  lp += __shfl_xor(lp, 32);
  const float l_run = lp;

  // ---- merge the two kv-half partials (exact flash combine), write ctx.
  float* Om = (float*)Kls;
  float* mls = (float*)Vls;

  __syncthreads();  // loop done; safe to reuse K/V LDS
  if (w >= 4) {
#pragma unroll
    for (int r = 0; r < 4; ++r) {
      const int rr = wg * 16 + 4 * g + r;
#pragma unroll
      for (int n = 0; n < 4; ++n) Om[rr * 64 + 16 * n + q] = oacc[n][r];
    }
    if (g == 0)
      *reinterpret_cast<float2*>(&mls[(wg * 16 + q) * 2]) =
          make_float2(m_run, l_run);
  }
  __syncthreads();
  if (w < 4) {
#pragma unroll
    for (int r = 0; r < 4; ++r) {
      const int rr = wg * 16 + 4 * g + r;
      const float m_own = __shfl(m_run, 4 * g + r, 16);
      const float l_own = __shfl(l_run, 4 * g + r, 16);
      const float2 ml2 = *reinterpret_cast<const float2*>(&mls[rr * 2]);
      const float ms = fmaxf(m_own, ml2.x);
      const float c1 = fexp2(m_own - ms);
      const float c2 = fexp2(ml2.x - ms);
      const float inv = 1.0f / (c1 * l_own + c2 * ml2.y);
      const int row = qbase + rr;
      unsigned short* crow = ctx + ((size_t)(b * Ll + row)) * Dd + h * 64 + q;
#pragma unroll
      for (int n = 0; n < 4; ++n) {
        const float o2 = Om[rr * 64 + 16 * n + q];
        crow[16 * n] = f2bf((c1 * oacc[n][r] + c2 * o2) * inv);
      }
    }
  }
}

// ---------------------------------------------------------------------------
// Row LayerNorm
// ---------------------------------------------------------------------------
__global__ __launch_bounds__(256) void ln_kernel(
    const float* __restrict__ y, const float* __restrict__ gamma,
    const float* __restrict__ beta, float* __restrict__ out) {
  const int row = blockIdx.x;
  const int tid = threadIdx.x;
  const float* yr = y + (size_t)row * Dd;

  float2 v = *reinterpret_cast<const float2*>(&yr[tid * 2]);
  float s = v.x + v.y;
  float qq = v.x * v.x + v.y * v.y;
#pragma unroll
  for (int off = 1; off < 64; off <<= 1) {
    s += __shfl_xor(s, off, 64);
    qq += __shfl_xor(qq, off, 64);
  }
  __shared__ float ss[4], qs[4];
  if ((tid & 63) == 0) { ss[tid >> 6] = s; qs[tid >> 6] = qq; }
  __syncthreads();
  s = (ss[0] + ss[1]) + (ss[2] + ss[3]);
  qq = (qs[0] + qs[1]) + (qs[2] + qs[3]);

  const float mu = s * (1.0f / Dd);
  const float var = qq * (1.0f / Dd) - mu * mu;
  const float rstd = rsqrtf(var + 1e-5f);

  float2 gmv = *reinterpret_cast<const float2*>(&gamma[tid * 2]);
  float2 bev = *reinterpret_cast<const float2*>(&beta[tid * 2]);
  float2 o;
  o.x = (v.x - mu) * rstd * gmv.x + bev.x;
  o.y = (v.y - mu) * rstd * gmv.y + bev.y;
  *reinterpret_cast<float2*>(&out[(size_t)row * Dd + tid * 2]) = o;
}

}  // namespace

extern "C" void kernel_launch(void* const* d_in, const int* in_sizes, int n_in,
                              void* d_out, int out_size, void* d_ws,
                              size_t ws_size, hipStream_t stream) {
  const float* x = (const float*)d_in[0];
  const float* w_in = (const float*)d_in[1];
  const float* b_in = (const float*)d_in[2];
  const float* w_out = (const float*)d_in[3];
  const float* b_out = (const float*)d_in[4];
  const float* gamma = (const float*)d_in[5];
  const float* beta = (const float*)d_in[6];
  const int* wsz = (const int*)d_in[7];
  float* out = (float*)d_out;

  unsigned short* ws16 = (unsigned short*)d_ws;
  unsigned short* qkvb = ws16;                       // 6291456 elems
  unsigned short* ctxb = ws16 + 6291456;             // 2097152
  unsigned short* xb = ws16 + 8388608;               // 2097152
  unsigned short* wb = ws16 + 10485760;              // 786432
  unsigned short* wob = ws16 + 11272192;             // 262144
  float* y = (float*)d_ws;  // aliases qkvb (dead after attention)

  dim3 blk(256);

  cvt_bf16<<<dim3(QUADS_TOT / 256), blk, 0, stream>>>(x, w_in, w_out, xb, wb,
                                                      wob);
  gemm_mfma<64, 512, 1536, true><<<dim3(12, 64), blk, 0, stream>>>(
      xb, wb, b_in, nullptr, qkvb, nullptr);
  attn_mfma<<<dim3(512), dim3(512), 0, stream>>>(qkvb, wsz, ctxb);
  gemm_mfma<64, 512, 512, false><<<dim3(4, 64), blk, 0, stream>>>(
      ctxb, wob, b_out, x, nullptr, y);
  ln_kernel<<<dim3(M), blk, 0, stream>>>(y, gamma, beta, out);
}